// Round 1
// baseline (93.822 us; speedup 1.0000x reference)
//
#include <hip/hip_runtime.h>
#include <math.h>

// RBF pairwise kernel: out[i,j] = var * exp(-0.5 * sum_d ((x[i,d]-xx[j,d])/s[d])^2)
// N=M=4096, D=16, fp32 in/out.
//
// R4: write-locality + SGPR-a restructure.
//   out[i,j] = exp2( x_i . b_j  - cc_i - dn_j ),  with
//     b_j  = xx_j * inv^2 * log2(e)        (per-lane registers, 16 float4)
//     cc_i = log2(e)*(0.5|x_i/s|^2 - lnvar) (LDS, 1 b32 broadcast per row)
//     dn_j = log2(e)*0.5|xx_j/s|^2          (per-lane registers)
//   so the hot loop reads the RAW x row at a block-uniform address ->
//   s_load into SGPRs, v_fmac with SGPR src; NO ds_read_b128 in the loop.
//
// Tile = 16 rows x 1024 cols (grid 4x256 = 1024 blocks = 4/CU):
//   - j in lanes: lane l of wave w owns j = j0 + 256w + 4l -> the 4 waves
//     co-write ADJACENT 1 KB chunks of the SAME output row each ii ->
//     4 KB contiguous bursts (vs 1 KB at 16 KB stride before). Targets the
//     observed 1.56 TB/s effective write BW (fill achieves 5.85 TB/s).
//   - i is block-uniform: all waves walk the same 16 rows; per-lane work
//     (16 ii x 4 j, 16 fma/output) identical to R3.
// VGPR ~90 (b 64 + acc/addr) -> no spill at the 128 cap of (256,4).

#define NN 4096
#define MM 4096
#define DD 16
#define L2E 1.44269504f     // log2(e)
#define HL2E 0.72134752f    // 0.5*log2(e)

__global__ __launch_bounds__(256, 4)
void rbf_kernel(const float* __restrict__ x, const float* __restrict__ xx,
                const float* __restrict__ scale_ff,
                const float* __restrict__ variance_ff,
                float* __restrict__ out) {
  __shared__ __align__(16) float s_inv[DD];  // 1/softplus(scale_ff)
  __shared__ __align__(16) float s_il[DD];   // inv * log2(e)
  __shared__ float s_lnvarL;                 // log2(e) * ln(softplus(var_ff))
  __shared__ float s_cc[16];                 // per-row constant

  const int tid  = threadIdx.x;
  const int lane = tid & 63;
  const int wave = tid >> 6;

  const int i0 = blockIdx.y * 16;    // 16 output rows per block
  const int j0 = blockIdx.x * 1024;  // 1024 output cols per block

  // phase 1: scales
  if (tid < DD) {
    const float sp  = log1pf(expf(scale_ff[tid]));
    const float inv = 1.0f / sp;
    s_inv[tid] = inv;
    s_il[tid]  = inv * L2E;
  }
  if (tid == DD) {
    s_lnvarL = L2E * logf(log1pf(expf(variance_ff[0])));
  }
  __syncthreads();

  // phase 2a: cc_i for the block's 16 x-rows (16 threads, coalesced 1 KB read)
  if (tid < 16) {
    float s = 0.f;
    const float* xp = x + (size_t)(i0 + tid) * DD;
#pragma unroll
    for (int c = 0; c < 4; ++c) {
      const float4 v  = *(const float4*)(xp + 4 * c);
      const float4 iv = *(const float4*)&s_inv[4 * c];
      const float ax = v.x * iv.x, ay = v.y * iv.y;
      const float az = v.z * iv.z, aw = v.w * iv.w;
      s = fmaf(ax, ax, s); s = fmaf(ay, ay, s);
      s = fmaf(az, az, s); s = fmaf(aw, aw, s);
    }
    s_cc[tid] = fmaf(HL2E, s, -s_lnvarL);   // L*(0.5|a|^2 - lnvar)
  }

  // phase 2b: per-lane xx fragment: 4 rows j = j0 + 256*wave + 4*lane .. +3
  float4 b[4][4];
  float ndn[4];
  {
    float4 iv[4], il[4];
#pragma unroll
    for (int c = 0; c < 4; ++c) {
      iv[c] = *(const float4*)&s_inv[4 * c];
      il[c] = *(const float4*)&s_il[4 * c];
    }
    const int jb = j0 + (wave << 8) + (lane << 2);
#pragma unroll
    for (int r = 0; r < 4; ++r) {
      float s = 0.f;
#pragma unroll
      for (int c = 0; c < 4; ++c) {
        const float4 v = *(const float4*)&xx[(size_t)(jb + r) * DD + 4 * c];
        const float tx = v.x * iv[c].x, ty = v.y * iv[c].y;
        const float tz = v.z * iv[c].z, tw = v.w * iv[c].w;
        s = fmaf(tx, tx, s); s = fmaf(ty, ty, s);
        s = fmaf(tz, tz, s); s = fmaf(tw, tw, s);
        b[r][c].x = tx * il[c].x; b[r][c].y = ty * il[c].y;
        b[r][c].z = tz * il[c].z; b[r][c].w = tw * il[c].w;
      }
      ndn[r] = -HL2E * s;                   // -L*0.5|b|^2
    }
  }

  __syncthreads();  // s_cc ready

  const int jb = j0 + (wave << 8) + (lane << 2);
  const float* __restrict__ xw = x + (size_t)i0 * DD;   // block-uniform
  float* __restrict__ op = out + (size_t)i0 * MM + jb;

#pragma unroll
  for (int ii = 0; ii < 16; ++ii) {
    // raw x row, block-uniform address -> scalar loads (SGPRs)
    const float4 a0 = *(const float4*)(xw + ii * DD + 0);
    const float4 a1 = *(const float4*)(xw + ii * DD + 4);
    const float4 a2 = *(const float4*)(xw + ii * DD + 8);
    const float4 a3 = *(const float4*)(xw + ii * DD + 12);
    const float cc  = s_cc[ii];             // 1 ds_read_b32 broadcast

    float acc[4];
#pragma unroll
    for (int r = 0; r < 4; ++r) acc[r] = ndn[r] - cc;

#pragma unroll
    for (int r = 0; r < 4; ++r) {
      float s = acc[r];
      s = fmaf(a0.x, b[r][0].x, s); s = fmaf(a0.y, b[r][0].y, s);
      s = fmaf(a0.z, b[r][0].z, s); s = fmaf(a0.w, b[r][0].w, s);
      s = fmaf(a1.x, b[r][1].x, s); s = fmaf(a1.y, b[r][1].y, s);
      s = fmaf(a1.z, b[r][1].z, s); s = fmaf(a1.w, b[r][1].w, s);
      s = fmaf(a2.x, b[r][2].x, s); s = fmaf(a2.y, b[r][2].y, s);
      s = fmaf(a2.z, b[r][2].z, s); s = fmaf(a2.w, b[r][2].w, s);
      s = fmaf(a3.x, b[r][3].x, s); s = fmaf(a3.y, b[r][3].y, s);
      s = fmaf(a3.w, b[r][3].w, s); s = fmaf(a3.z, b[r][3].z, s);
      acc[r] = s;
    }

    float4 o;
    o.x = __builtin_amdgcn_exp2f(acc[0]);
    o.y = __builtin_amdgcn_exp2f(acc[1]);
    o.z = __builtin_amdgcn_exp2f(acc[2]);
    o.w = __builtin_amdgcn_exp2f(acc[3]);
    *(float4*)(op + (size_t)ii * MM) = o;   // waves 0..3 adjacent -> 4 KB burst
  }
}

extern "C" void kernel_launch(void* const* d_in, const int* in_sizes, int n_in,
                              void* d_out, int out_size, void* d_ws, size_t ws_size,
                              hipStream_t stream) {
  const float* x   = (const float*)d_in[0];   // [4096,16]
  const float* xx  = (const float*)d_in[1];   // [4096,16]
  const float* sc  = (const float*)d_in[2];   // [16]
  const float* var = (const float*)d_in[3];   // [1]
  float* out = (float*)d_out;                 // [4096,4096]

  dim3 grid(MM / 1024, NN / 16);              // (4, 256) = 1024 blocks = 4/CU
  dim3 block(256);
  rbf_kernel<<<grid, block, 0, stream>>>(x, xx, sc, var, out);
}